// Round 4
// baseline (826.392 us; speedup 1.0000x reference)
//
#include <hip/hip_runtime.h>
#include <hip/hip_bf16.h>
#include <math.h>

#define N_NODES 100000
#define N_EDGES 1600000
#define IN_DIM  768
#define HIDDEN  256

#define SCAN_B  256
#define N_SBLK  ((N_NODES + SCAN_B - 1) / SCAN_B)   // 391

// ---- ws layout (bytes), all offsets 16B-aligned ----
#define H_OFF    0ull                  // bf16 h' [N_NODES][HIDDEN]     51,200,000 B
#define ADJ_OFF  51200000ull           // int adj [N_EDGES]              6,400,000 B
#define RS_OFF   57600000ull           // int row_start [N_NODES+1]        400,004 B
#define CUR_OFF  58000016ull           // int cursor [N_NODES]             400,000 B
#define DEG_OFF  58400016ull           // int deg [N_NODES]                400,000 B
#define DINV_OFF 58800016ull           // float dinv [N_NODES]             400,000 B
#define W1T_OFF  59200016ull           // bf16 W1t [HIDDEN][IN_DIM]        393,216 B
#define BSUM_OFF 59593232ull           // int bsum [N_SBLK]                  1,564 B
// total ~59.6 MB

typedef short          bf16x8 __attribute__((ext_vector_type(8)));
typedef float          fp32x4 __attribute__((ext_vector_type(4)));
typedef float          fp32x8 __attribute__((ext_vector_type(8)));
typedef unsigned short u16x8  __attribute__((ext_vector_type(8)));

__device__ inline short f2bf(float f) {
    union { float f; unsigned u; } c; c.f = f;
    unsigned u = c.u;
    unsigned r = u + 0x7FFFu + ((u >> 16) & 1u);   // RNE
    return (short)(r >> 16);
}

__device__ inline fp32x8 bf8_to_f8(u16x8 v) {
    fp32x8 r;
    for (int j = 0; j < 8; j++) {
        union { unsigned u; float f; } c;
        c.u = ((unsigned)v[j]) << 16;
        r[j] = c.f;
    }
    return r;
}

// async global->LDS, 16B per lane; LDS dest = wave-uniform base + lane*16
__device__ inline void gl_lds16(const short* g, short* l) {
    __builtin_amdgcn_global_load_lds(
        (const __attribute__((address_space(1))) unsigned int*)g,
        (__attribute__((address_space(3))) unsigned int*)l, 16, 0, 0);
}

// ---------------- init: zero deg + cursor ----------------
__global__ void init_kernel(int* __restrict__ deg, int* __restrict__ cursor) {
    int i = blockIdx.x * blockDim.x + threadIdx.x;
    if (i < N_NODES) { deg[i] = 0; cursor[i] = 0; }
}

// ---------------- W1 -> W1t (bf16, [HIDDEN][IN_DIM]) ----------------
__global__ void w1t_kernel(const float* __restrict__ w1, short* __restrict__ w1t) {
    int i = blockIdx.x * blockDim.x + threadIdx.x;
    if (i < HIDDEN * IN_DIM) {
        int n = i / IN_DIM, k = i % IN_DIM;
        w1t[i] = f2bf(w1[(size_t)k * HIDDEN + n]);
    }
}

// ---------------- count in-degree (real edges only) ----------------
__global__ void count_kernel(const int* __restrict__ dst, int* __restrict__ deg) {
    int e = blockIdx.x * blockDim.x + threadIdx.x;
    if (e < N_EDGES) atomicAdd(&deg[dst[e]], 1);
}

// ---------------- scan phase 1: per-block sums ----------------
__global__ __launch_bounds__(SCAN_B) void scan1_kernel(const int* __restrict__ deg,
                                                       int* __restrict__ bsum) {
    int i = blockIdx.x * SCAN_B + threadIdx.x;
    int v = (i < N_NODES) ? deg[i] : 0;
    for (int off = 32; off > 0; off >>= 1) v += __shfl_down(v, off, 64);
    __shared__ int wsum[SCAN_B / 64];
    int lane = threadIdx.x & 63, w = threadIdx.x >> 6;
    if (lane == 0) wsum[w] = v;
    __syncthreads();
    if (threadIdx.x == 0) {
        int s = 0;
        for (int j = 0; j < SCAN_B / 64; j++) s += wsum[j];
        bsum[blockIdx.x] = s;
    }
}

// ---------------- scan phase 2: exclusive-scan the block sums (1 block) ----------------
__global__ __launch_bounds__(512) void scan2_kernel(int* __restrict__ bsum) {
    __shared__ int s[512];
    int tid = threadIdx.x;
    int v = (tid < N_SBLK) ? bsum[tid] : 0;
    s[tid] = v;
    __syncthreads();
    for (int off = 1; off < 512; off <<= 1) {
        int t = (tid >= off) ? s[tid - off] : 0;
        __syncthreads();
        s[tid] += t;
        __syncthreads();
    }
    if (tid < N_SBLK) bsum[tid] = s[tid] - v;   // exclusive
}

// ---------------- scan phase 3: block-local scan + offset; also dinv ----------------
__global__ __launch_bounds__(SCAN_B) void scan3_kernel(const int* __restrict__ deg,
                                                       const int* __restrict__ bsum,
                                                       int* __restrict__ row_start,
                                                       float* __restrict__ dinv) {
    __shared__ int s[SCAN_B];
    int i = blockIdx.x * SCAN_B + threadIdx.x;
    int tid = threadIdx.x;
    int d = (i < N_NODES) ? deg[i] : 0;
    s[tid] = d;
    __syncthreads();
    for (int off = 1; off < SCAN_B; off <<= 1) {
        int t = (tid >= off) ? s[tid - off] : 0;
        __syncthreads();
        s[tid] += t;
        __syncthreads();
    }
    if (i < N_NODES) {
        row_start[i] = bsum[blockIdx.x] + s[tid] - d;   // exclusive
        dinv[i] = rsqrtf((float)(d + 1));               // +1 self loop
        if (i == N_NODES - 1) row_start[N_NODES] = N_EDGES;  // deg sums to N_EDGES
    }
}

// ---------------- fill CSR adjacency (src list grouped by dst) ----------------
__global__ void fill_kernel(const int* __restrict__ src, const int* __restrict__ dst,
                            const int* __restrict__ row_start, int* __restrict__ cursor,
                            int* __restrict__ adj) {
    int e = blockIdx.x * blockDim.x + threadIdx.x;
    if (e < N_EDGES) {
        int d = dst[e];
        int p = row_start[d] + atomicAdd(&cursor[d], 1);
        adj[p] = src[e];
    }
}

// ---------------- GEMM1: h'[r] = bf16(dinv[r] * (x[r] @ W1)) ----------------
// 128x128 tile, BK=32. K-major-chunked LDS layout: slot = q*128 + row, 8 shorts
// per slot -> bank start = slot*4 mod 32 -> consecutive slots per 16-lane phase
// = 2-way (free) for frag reads AND staging writes. LDS double-buffered, single
// barrier per K-iter. B staged via global_load_lds (16B, async, no VGPR trip);
// A staged via regs (needs fp32->bf16 convert).
__global__ __launch_bounds__(256) void gemm1_kernel(const float* __restrict__ x,
                                                    const short* __restrict__ w1t,
                                                    const float* __restrict__ dinv,
                                                    unsigned short* __restrict__ h) {
    __shared__ __attribute__((aligned(16))) short a_lds[2][4096];  // [buf][slot*8+j]
    __shared__ __attribute__((aligned(16))) short b_lds[2][4096];

    const int tid  = threadIdx.x;
    const int lane = tid & 63;
    const int wave = tid >> 6;
    const int wm = (wave >> 1) * 64;
    const int wn = (wave & 1) * 64;
    const int l15 = lane & 15;
    const int q   = lane >> 4;
    const int row0 = blockIdx.x * 128;
    const int col0 = blockIdx.y * 128;

    // A staging: thread handles row = tid&127, chunks aq = (tid>>7)*2 and aq+1
    // -> one contiguous 64B (16 fp32) global read per thread per K-tile.
    const int arow = tid & 127;
    const int aq   = (tid >> 7) * 2;
    const int agr  = row0 + arow;
    const bool aok = agr < N_NODES;
    const float* axp = x + (size_t)agr * IN_DIM + aq * 8;

    // B staging: slot s holds w1t[col0 + (s&127)][k0 + (s>>7)*8 .. +8]
    const int bslot0 = wave * 64 + lane;          // 0..255
    const int bslot1 = 256 + wave * 64 + lane;    // 256..511
    const short* bgp0 = w1t + (size_t)(col0 + (bslot0 & 127)) * IN_DIM + (bslot0 >> 7) * 8;
    const short* bgp1 = w1t + (size_t)(col0 + (bslot1 & 127)) * IN_DIM + (bslot1 >> 7) * 8;
    short* const bl0base0 = &b_lds[0][(size_t)(wave * 64) * 8];
    short* const bl0base1 = &b_lds[0][(size_t)(256 + wave * 64) * 8];
    short* const bl1base0 = &b_lds[1][(size_t)(wave * 64) * 8];
    short* const bl1base1 = &b_lds[1][(size_t)(256 + wave * 64) * 8];

    fp32x4 acc[4][4];
    for (int i = 0; i < 4; i++)
        for (int j = 0; j < 4; j++)
            for (int r = 0; r < 4; r++) acc[i][j][r] = 0.0f;

    // ---- prologue: stage tile k0=0 into buf 0 ----
    gl_lds16(bgp0, bl0base0);
    gl_lds16(bgp1, bl0base1);
    {
        fp32x4 p0 = {0,0,0,0}, p1 = {0,0,0,0}, p2 = {0,0,0,0}, p3 = {0,0,0,0};
        if (aok) {
            p0 = *(const fp32x4*)axp;       p1 = *(const fp32x4*)(axp + 4);
            p2 = *(const fp32x4*)(axp + 8); p3 = *(const fp32x4*)(axp + 12);
        }
        bf16x8 av;
        av[0]=f2bf(p0[0]); av[1]=f2bf(p0[1]); av[2]=f2bf(p0[2]); av[3]=f2bf(p0[3]);
        av[4]=f2bf(p1[0]); av[5]=f2bf(p1[1]); av[6]=f2bf(p1[2]); av[7]=f2bf(p1[3]);
        *(bf16x8*)(&a_lds[0][(size_t)(aq * 128 + arow) * 8]) = av;
        av[0]=f2bf(p2[0]); av[1]=f2bf(p2[1]); av[2]=f2bf(p2[2]); av[3]=f2bf(p2[3]);
        av[4]=f2bf(p3[0]); av[5]=f2bf(p3[1]); av[6]=f2bf(p3[2]); av[7]=f2bf(p3[3]);
        *(bf16x8*)(&a_lds[0][(size_t)((aq + 1) * 128 + arow) * 8]) = av;
    }

    int cur = 0;
    for (int k0 = 0; k0 < IN_DIM; k0 += 32) {
        __syncthreads();   // buf[cur] ready (prev ds_writes + global_load_lds drained)
        const int nxt = cur ^ 1;
        const bool more = (k0 + 32) < IN_DIM;

        fp32x4 p0, p1, p2, p3;
        if (more) {
            // async B prefetch into buf[nxt]
            gl_lds16(bgp0 + k0 + 32, nxt ? bl1base0 : bl0base0);
            gl_lds16(bgp1 + k0 + 32, nxt ? bl1base1 : bl0base1);
            // A prefetch into regs
            if (aok) {
                const float* p = axp + k0 + 32;
                p0 = *(const fp32x4*)p;       p1 = *(const fp32x4*)(p + 4);
                p2 = *(const fp32x4*)(p + 8); p3 = *(const fp32x4*)(p + 12);
            } else {
                p0 = p1 = p2 = p3 = (fp32x4){0,0,0,0};
            }
        }

        // compute on buf[cur]
        bf16x8 af[4], bfr[4];
        for (int mt = 0; mt < 4; mt++)
            af[mt] = *(const bf16x8*)(&a_lds[cur][(size_t)(q * 128 + wm + mt * 16 + l15) * 8]);
        for (int nt = 0; nt < 4; nt++)
            bfr[nt] = *(const bf16x8*)(&b_lds[cur][(size_t)(q * 128 + wn + nt * 16 + l15) * 8]);
        for (int mt = 0; mt < 4; mt++)
            for (int nt = 0; nt < 4; nt++)
                acc[mt][nt] = __builtin_amdgcn_mfma_f32_16x16x32_bf16(
                    af[mt], bfr[nt], acc[mt][nt], 0, 0, 0);

        if (more) {
            // commit A prefetch to buf[nxt] (vmcnt wait lands after MFMAs issued)
            bf16x8 av;
            av[0]=f2bf(p0[0]); av[1]=f2bf(p0[1]); av[2]=f2bf(p0[2]); av[3]=f2bf(p0[3]);
            av[4]=f2bf(p1[0]); av[5]=f2bf(p1[1]); av[6]=f2bf(p1[2]); av[7]=f2bf(p1[3]);
            *(bf16x8*)(&a_lds[nxt][(size_t)(aq * 128 + arow) * 8]) = av;
            av[0]=f2bf(p2[0]); av[1]=f2bf(p2[1]); av[2]=f2bf(p2[2]); av[3]=f2bf(p2[3]);
            av[4]=f2bf(p3[0]); av[5]=f2bf(p3[1]); av[6]=f2bf(p3[2]); av[7]=f2bf(p3[3]);
            *(bf16x8*)(&a_lds[nxt][(size_t)((aq + 1) * 128 + arow) * 8]) = av;
        }
        cur = nxt;
    }

    // epilogue: h'[row][col] = bf16(dinv[row] * acc)
    float dv[4][4];
    for (int mt = 0; mt < 4; mt++)
        for (int r = 0; r < 4; r++) {
            int row = row0 + wm + mt * 16 + q * 4 + r;
            dv[mt][r] = (row < N_NODES) ? dinv[row] : 0.0f;
        }
    for (int mt = 0; mt < 4; mt++) {
        for (int nt = 0; nt < 4; nt++) {
            int col = col0 + wn + nt * 16 + l15;
            for (int r = 0; r < 4; r++) {
                int row = row0 + wm + mt * 16 + q * 4 + r;
                if (row < N_NODES)
                    h[(size_t)row * HIDDEN + col] =
                        (unsigned short)f2bf(dv[mt][r] * acc[mt][nt][r]);
            }
        }
    }
}

// ---------------- aggregate + bias + relu + W2 + log_softmax ----------------
// 2 nodes per wave (32 lanes each), 8 channels/lane -> 16B u16x8 gathers,
// x4 unroll per half-wave => 8 independent 16B loads in flight per wave.
__global__ __launch_bounds__(256) void aggregate_kernel(
    const unsigned short* __restrict__ h, const int* __restrict__ adj,
    const int* __restrict__ row_start, const float* __restrict__ dinv,
    const float* __restrict__ b1, const float* __restrict__ w2,
    const float* __restrict__ b2, float* __restrict__ out) {
    const int lane = threadIdx.x & 63;
    const int wave = threadIdx.x >> 6;
    const int half = lane >> 5;
    const int l32  = lane & 31;
    const int v = blockIdx.x * 8 + wave * 2 + half;   // grid covers exactly N_NODES

    const size_t choff = (size_t)l32 * 8;

    // self-loop term: h'[v] (already dinv[v]*h[v])
    fp32x8 a0 = bf8_to_f8(*(const u16x8*)(h + (size_t)v * HIDDEN + choff));
    fp32x8 a1 = {0,0,0,0,0,0,0,0}, a2 = a1, a3 = a1;

    int e0 = row_start[v], e1 = row_start[v + 1];
    for (int e = e0; e < e1; e += 32) {
        int cnt = min(32, e1 - e);
        int s = (l32 < cnt) ? adj[e + l32] : 0;
        int i = 0;
        for (; i + 4 <= cnt; i += 4) {
            int s0 = __shfl(s, i,     32);
            int s1 = __shfl(s, i + 1, 32);
            int s2 = __shfl(s, i + 2, 32);
            int s3 = __shfl(s, i + 3, 32);
            u16x8 r0 = *(const u16x8*)(h + (size_t)s0 * HIDDEN + choff);
            u16x8 r1 = *(const u16x8*)(h + (size_t)s1 * HIDDEN + choff);
            u16x8 r2 = *(const u16x8*)(h + (size_t)s2 * HIDDEN + choff);
            u16x8 r3 = *(const u16x8*)(h + (size_t)s3 * HIDDEN + choff);
            a0 += bf8_to_f8(r0);
            a1 += bf8_to_f8(r1);
            a2 += bf8_to_f8(r2);
            a3 += bf8_to_f8(r3);
        }
        for (; i < cnt; i++) {
            int si = __shfl(s, i, 32);
            a0 += bf8_to_f8(*(const u16x8*)(h + (size_t)si * HIDDEN + choff));
        }
    }
    fp32x8 acc = (a0 + a1) + (a2 + a3);

    float dvv = dinv[v];
    float hr[8];
    for (int j = 0; j < 8; j++)
        hr[j] = fmaxf(0.0f, dvv * acc[j] + b1[choff + j]);

    float p0 = 0.f, p1 = 0.f, p2 = 0.f;
    for (int j = 0; j < 8; j++) {
        const float* wr = w2 + (choff + j) * 3;
        p0 += hr[j] * wr[0];
        p1 += hr[j] * wr[1];
        p2 += hr[j] * wr[2];
    }
    for (int off = 16; off > 0; off >>= 1) {
        p0 += __shfl_down(p0, off, 32);
        p1 += __shfl_down(p1, off, 32);
        p2 += __shfl_down(p2, off, 32);
    }
    if (l32 == 0) {
        p0 += b2[0]; p1 += b2[1]; p2 += b2[2];
        float m = fmaxf(p0, fmaxf(p1, p2));
        float l = logf(expf(p0 - m) + expf(p1 - m) + expf(p2 - m));
        out[(size_t)v * 3 + 0] = p0 - m - l;
        out[(size_t)v * 3 + 1] = p1 - m - l;
        out[(size_t)v * 3 + 2] = p2 - m - l;
    }
}

extern "C" void kernel_launch(void* const* d_in, const int* in_sizes, int n_in,
                              void* d_out, int out_size, void* d_ws, size_t ws_size,
                              hipStream_t stream) {
    const float* x    = (const float*)d_in[0];
    const int*   ei   = (const int*)d_in[1];      // [2][N_EDGES]
    const float* W1   = (const float*)d_in[2];
    const float* b1   = (const float*)d_in[3];
    const float* W2   = (const float*)d_in[4];
    const float* b2   = (const float*)d_in[5];
    float* out = (float*)d_out;

    const int* src = ei;
    const int* dst = ei + N_EDGES;

    char* ws = (char*)d_ws;
    unsigned short* h_ws = (unsigned short*)(ws + H_OFF);
    int*   adj       = (int*)(ws + ADJ_OFF);
    int*   row_start = (int*)(ws + RS_OFF);
    int*   cursor    = (int*)(ws + CUR_OFF);
    int*   deg       = (int*)(ws + DEG_OFF);
    float* dinv      = (float*)(ws + DINV_OFF);
    short* w1t       = (short*)(ws + W1T_OFF);
    int*   bsum      = (int*)(ws + BSUM_OFF);

    init_kernel<<<(N_NODES + 255) / 256, 256, 0, stream>>>(deg, cursor);
    w1t_kernel<<<(HIDDEN * IN_DIM + 255) / 256, 256, 0, stream>>>(W1, w1t);
    count_kernel<<<(N_EDGES + 255) / 256, 256, 0, stream>>>(dst, deg);
    scan1_kernel<<<N_SBLK, SCAN_B, 0, stream>>>(deg, bsum);
    scan2_kernel<<<1, 512, 0, stream>>>(bsum);
    scan3_kernel<<<N_SBLK, SCAN_B, 0, stream>>>(deg, bsum, row_start, dinv);
    fill_kernel<<<(N_EDGES + 255) / 256, 256, 0, stream>>>(src, dst, row_start, cursor, adj);
    gemm1_kernel<<<dim3((N_NODES + 127) / 128, HIDDEN / 128), 256, 0, stream>>>(x, w1t, dinv, h_ws);
    aggregate_kernel<<<N_NODES / 8, 256, 0, stream>>>(h_ws, adj, row_start, dinv, b1, W2, b2, out);
}

// Round 5
// 823.188 us; speedup vs baseline: 1.0039x; 1.0039x over previous
//
#include <hip/hip_runtime.h>
#include <hip/hip_bf16.h>
#include <math.h>

#define N_NODES 100000
#define N_EDGES 1600000
#define IN_DIM  768
#define HIDDEN  256

#define SCAN_B  256
#define N_SBLK  ((N_NODES + SCAN_B - 1) / SCAN_B)   // 391

// ---- ws layout (bytes), all offsets 16B-aligned ----
#define H_OFF    0ull                  // bf16 h' [N_NODES][HIDDEN]     51,200,000 B
#define ADJ_OFF  51200000ull           // int adj [N_EDGES]              6,400,000 B
#define RS_OFF   57600000ull           // int row_start [N_NODES+1]        400,004 B
#define CUR_OFF  58000016ull           // int cursor [N_NODES]             400,000 B
#define DEG_OFF  58400016ull           // int deg [N_NODES]                400,000 B
#define DINV_OFF 58800016ull           // float dinv [N_NODES]             400,000 B
#define W1T_OFF  59200016ull           // bf16 W1t [HIDDEN][IN_DIM]        393,216 B
#define BSUM_OFF 59593232ull           // int bsum [N_SBLK]                  1,564 B
// total ~59.6 MB

typedef short          bf16x8 __attribute__((ext_vector_type(8)));
typedef float          fp32x4 __attribute__((ext_vector_type(4)));
typedef float          fp32x8 __attribute__((ext_vector_type(8)));
typedef unsigned short u16x8  __attribute__((ext_vector_type(8)));

__device__ inline short f2bf(float f) {
    union { float f; unsigned u; } c; c.f = f;
    unsigned u = c.u;
    unsigned r = u + 0x7FFFu + ((u >> 16) & 1u);   // RNE
    return (short)(r >> 16);
}

// packed fp32x2 -> bf16x2 (v_cvt_pk_bf16_f32 on gfx950), RNE
__device__ inline unsigned pk2(float x, float y) {
    __hip_bfloat162 h = __float22bfloat162_rn(make_float2(x, y));
    union { __hip_bfloat162 h2; unsigned u; } c;
    c.h2 = h;
    return c.u;
}

__device__ inline bf16x8 cvt8(fp32x4 a, fp32x4 b) {
    union { bf16x8 v; unsigned u[4]; } r;
    r.u[0] = pk2(a[0], a[1]);
    r.u[1] = pk2(a[2], a[3]);
    r.u[2] = pk2(b[0], b[1]);
    r.u[3] = pk2(b[2], b[3]);
    return r.v;
}

__device__ inline fp32x8 bf8_to_f8(u16x8 v) {
    fp32x8 r;
    for (int j = 0; j < 8; j++) {
        union { unsigned u; float f; } c;
        c.u = ((unsigned)v[j]) << 16;
        r[j] = c.f;
    }
    return r;
}

// ---------------- init: zero deg + cursor ----------------
__global__ void init_kernel(int* __restrict__ deg, int* __restrict__ cursor) {
    int i = blockIdx.x * blockDim.x + threadIdx.x;
    if (i < N_NODES) { deg[i] = 0; cursor[i] = 0; }
}

// ---------------- W1 -> W1t (bf16, [HIDDEN][IN_DIM]) ----------------
__global__ void w1t_kernel(const float* __restrict__ w1, short* __restrict__ w1t) {
    int i = blockIdx.x * blockDim.x + threadIdx.x;
    if (i < HIDDEN * IN_DIM) {
        int n = i / IN_DIM, k = i % IN_DIM;
        w1t[i] = f2bf(w1[(size_t)k * HIDDEN + n]);
    }
}

// ---------------- count in-degree (real edges only) ----------------
__global__ void count_kernel(const int* __restrict__ dst, int* __restrict__ deg) {
    int e = blockIdx.x * blockDim.x + threadIdx.x;
    if (e < N_EDGES) atomicAdd(&deg[dst[e]], 1);
}

// ---------------- scan phase 1: per-block sums ----------------
__global__ __launch_bounds__(SCAN_B) void scan1_kernel(const int* __restrict__ deg,
                                                       int* __restrict__ bsum) {
    int i = blockIdx.x * SCAN_B + threadIdx.x;
    int v = (i < N_NODES) ? deg[i] : 0;
    for (int off = 32; off > 0; off >>= 1) v += __shfl_down(v, off, 64);
    __shared__ int wsum[SCAN_B / 64];
    int lane = threadIdx.x & 63, w = threadIdx.x >> 6;
    if (lane == 0) wsum[w] = v;
    __syncthreads();
    if (threadIdx.x == 0) {
        int s = 0;
        for (int j = 0; j < SCAN_B / 64; j++) s += wsum[j];
        bsum[blockIdx.x] = s;
    }
}

// ---------------- scan phase 2: exclusive-scan the block sums (1 block) ----------------
__global__ __launch_bounds__(512) void scan2_kernel(int* __restrict__ bsum) {
    __shared__ int s[512];
    int tid = threadIdx.x;
    int v = (tid < N_SBLK) ? bsum[tid] : 0;
    s[tid] = v;
    __syncthreads();
    for (int off = 1; off < 512; off <<= 1) {
        int t = (tid >= off) ? s[tid - off] : 0;
        __syncthreads();
        s[tid] += t;
        __syncthreads();
    }
    if (tid < N_SBLK) bsum[tid] = s[tid] - v;   // exclusive
}

// ---------------- scan phase 3: block-local scan + offset; also dinv ----------------
__global__ __launch_bounds__(SCAN_B) void scan3_kernel(const int* __restrict__ deg,
                                                       const int* __restrict__ bsum,
                                                       int* __restrict__ row_start,
                                                       float* __restrict__ dinv) {
    __shared__ int s[SCAN_B];
    int i = blockIdx.x * SCAN_B + threadIdx.x;
    int tid = threadIdx.x;
    int d = (i < N_NODES) ? deg[i] : 0;
    s[tid] = d;
    __syncthreads();
    for (int off = 1; off < SCAN_B; off <<= 1) {
        int t = (tid >= off) ? s[tid - off] : 0;
        __syncthreads();
        s[tid] += t;
        __syncthreads();
    }
    if (i < N_NODES) {
        row_start[i] = bsum[blockIdx.x] + s[tid] - d;   // exclusive
        dinv[i] = rsqrtf((float)(d + 1));               // +1 self loop
        if (i == N_NODES - 1) row_start[N_NODES] = N_EDGES;  // deg sums to N_EDGES
    }
}

// ---------------- fill CSR adjacency (src list grouped by dst) ----------------
__global__ void fill_kernel(const int* __restrict__ src, const int* __restrict__ dst,
                            const int* __restrict__ row_start, int* __restrict__ cursor,
                            int* __restrict__ adj) {
    int e = blockIdx.x * blockDim.x + threadIdx.x;
    if (e < N_EDGES) {
        int d = dst[e];
        int p = row_start[d] + atomicAdd(&cursor[d], 1);
        adj[p] = src[e];
    }
}

// ---------------- GEMM1: h'[r] = bf16(dinv[r] * (x[r] @ W1)) ----------------
// 128x128 tile, BK=32, single LDS buffer in K-chunked layout (slot = q*128+row,
// 16 B/slot; consecutive slots per 16-lane phase -> 2-way bank access = free,
// verified 0 conflicts in R4). R3's proven flow: commit regs->LDS, barrier,
// prefetch next K-tile into regs (overlaps MFMA), frag reads + MFMA, barrier.
// A staging: one contiguous 64 B fp32 read/thread, packed cvt to bf16.
__global__ __launch_bounds__(256) void gemm1_kernel(const float* __restrict__ x,
                                                    const short* __restrict__ w1t,
                                                    const float* __restrict__ dinv,
                                                    unsigned short* __restrict__ h) {
    __shared__ __attribute__((aligned(16))) short a_lds[4096];  // [slot*8+j], 512 slots
    __shared__ __attribute__((aligned(16))) short b_lds[4096];

    const int tid  = threadIdx.x;
    const int lane = tid & 63;
    const int wave = tid >> 6;
    const int wm = (wave >> 1) * 64;
    const int wn = (wave & 1) * 64;
    const int l15 = lane & 15;
    const int q   = lane >> 4;
    const int row0 = blockIdx.x * 128;
    const int col0 = blockIdx.y * 128;

    // A staging: thread covers row = tid&127, k-chunks aq and aq+1 (16 fp32 = 64 B).
    const int arow = tid & 127;
    const int aq   = (tid >> 7) * 2;
    const int agr  = row0 + arow;
    const bool aok = agr < N_NODES;
    const float* axp = x + (size_t)agr * IN_DIM + aq * 8;

    // B staging: slot s holds w1t[col0 + (s&127)][k0 + (s>>7)*8 .. +8]
    const int bslot0 = wave * 64 + lane;          // 0..255
    const int bslot1 = 256 + wave * 64 + lane;    // 256..511
    const short* bgp0 = w1t + (size_t)(col0 + (bslot0 & 127)) * IN_DIM + (bslot0 >> 7) * 8;
    const short* bgp1 = w1t + (size_t)(col0 + (bslot1 & 127)) * IN_DIM + (bslot1 >> 7) * 8;

    fp32x4 acc[4][4];
    for (int i = 0; i < 4; i++)
        for (int j = 0; j < 4; j++)
            for (int r = 0; r < 4; r++) acc[i][j][r] = 0.0f;

    // prefetch tile k0=0 into regs
    fp32x4 p0 = {0,0,0,0}, p1 = {0,0,0,0}, p2 = {0,0,0,0}, p3 = {0,0,0,0};
    if (aok) {
        p0 = *(const fp32x4*)axp;       p1 = *(const fp32x4*)(axp + 4);
        p2 = *(const fp32x4*)(axp + 8); p3 = *(const fp32x4*)(axp + 12);
    }
    bf16x8 pb0 = *(const bf16x8*)bgp0;
    bf16x8 pb1 = *(const bf16x8*)bgp1;

    for (int k0 = 0; k0 < IN_DIM; k0 += 32) {
        // commit prefetched tile to LDS (packed fp32->bf16 for A)
        *(bf16x8*)(&a_lds[(size_t)(aq * 128 + arow) * 8])       = cvt8(p0, p1);
        *(bf16x8*)(&a_lds[(size_t)((aq + 1) * 128 + arow) * 8]) = cvt8(p2, p3);
        *(bf16x8*)(&b_lds[(size_t)bslot0 * 8]) = pb0;
        *(bf16x8*)(&b_lds[(size_t)bslot1 * 8]) = pb1;
        __syncthreads();

        // prefetch next tile into regs (overlaps MFMA below)
        int kn = k0 + 32;
        if (kn < IN_DIM) {
            if (aok) {
                const float* p = axp + kn;
                p0 = *(const fp32x4*)p;       p1 = *(const fp32x4*)(p + 4);
                p2 = *(const fp32x4*)(p + 8); p3 = *(const fp32x4*)(p + 12);
            }
            pb0 = *(const bf16x8*)(bgp0 + kn);
            pb1 = *(const bf16x8*)(bgp1 + kn);
        }

        // frag reads (chunked layout: slot = q*128 + row) + MFMA
        bf16x8 af[4], bfr[4];
        for (int mt = 0; mt < 4; mt++)
            af[mt] = *(const bf16x8*)(&a_lds[(size_t)(q * 128 + wm + mt * 16 + l15) * 8]);
        for (int nt = 0; nt < 4; nt++)
            bfr[nt] = *(const bf16x8*)(&b_lds[(size_t)(q * 128 + wn + nt * 16 + l15) * 8]);
        for (int mt = 0; mt < 4; mt++)
            for (int nt = 0; nt < 4; nt++)
                acc[mt][nt] = __builtin_amdgcn_mfma_f32_16x16x32_bf16(
                    af[mt], bfr[nt], acc[mt][nt], 0, 0, 0);
        __syncthreads();
    }

    // epilogue: h'[row][col] = bf16(dinv[row] * acc)
    float dv[4][4];
    for (int mt = 0; mt < 4; mt++)
        for (int r = 0; r < 4; r++) {
            int row = row0 + wm + mt * 16 + q * 4 + r;
            dv[mt][r] = (row < N_NODES) ? dinv[row] : 0.0f;
        }
    for (int mt = 0; mt < 4; mt++) {
        for (int nt = 0; nt < 4; nt++) {
            int col = col0 + wn + nt * 16 + l15;
            for (int r = 0; r < 4; r++) {
                int row = row0 + wm + mt * 16 + q * 4 + r;
                if (row < N_NODES)
                    h[(size_t)row * HIDDEN + col] =
                        (unsigned short)f2bf(dv[mt][r] * acc[mt][nt][r]);
            }
        }
    }
}

// ---------------- aggregate + bias + relu + W2 + log_softmax ----------------
// 2 nodes per wave (32 lanes each), 8 channels/lane -> 16B u16x8 gathers,
// x4 unroll per half-wave => 8 independent 16B loads in flight per wave.
__global__ __launch_bounds__(256) void aggregate_kernel(
    const unsigned short* __restrict__ h, const int* __restrict__ adj,
    const int* __restrict__ row_start, const float* __restrict__ dinv,
    const float* __restrict__ b1, const float* __restrict__ w2,
    const float* __restrict__ b2, float* __restrict__ out) {
    const int lane = threadIdx.x & 63;
    const int wave = threadIdx.x >> 6;
    const int half = lane >> 5;
    const int l32  = lane & 31;
    const int v = blockIdx.x * 8 + wave * 2 + half;   // grid covers exactly N_NODES

    const size_t choff = (size_t)l32 * 8;

    // self-loop term: h'[v] (already dinv[v]*h[v])
    fp32x8 a0 = bf8_to_f8(*(const u16x8*)(h + (size_t)v * HIDDEN + choff));
    fp32x8 a1 = {0,0,0,0,0,0,0,0}, a2 = a1, a3 = a1;

    int e0 = row_start[v], e1 = row_start[v + 1];
    for (int e = e0; e < e1; e += 32) {
        int cnt = min(32, e1 - e);
        int s = (l32 < cnt) ? adj[e + l32] : 0;
        int i = 0;
        for (; i + 4 <= cnt; i += 4) {
            int s0 = __shfl(s, i,     32);
            int s1 = __shfl(s, i + 1, 32);
            int s2 = __shfl(s, i + 2, 32);
            int s3 = __shfl(s, i + 3, 32);
            u16x8 r0 = *(const u16x8*)(h + (size_t)s0 * HIDDEN + choff);
            u16x8 r1 = *(const u16x8*)(h + (size_t)s1 * HIDDEN + choff);
            u16x8 r2 = *(const u16x8*)(h + (size_t)s2 * HIDDEN + choff);
            u16x8 r3 = *(const u16x8*)(h + (size_t)s3 * HIDDEN + choff);
            a0 += bf8_to_f8(r0);
            a1 += bf8_to_f8(r1);
            a2 += bf8_to_f8(r2);
            a3 += bf8_to_f8(r3);
        }
        for (; i < cnt; i++) {
            int si = __shfl(s, i, 32);
            a0 += bf8_to_f8(*(const u16x8*)(h + (size_t)si * HIDDEN + choff));
        }
    }
    fp32x8 acc = (a0 + a1) + (a2 + a3);

    float dvv = dinv[v];
    float hr[8];
    for (int j = 0; j < 8; j++)
        hr[j] = fmaxf(0.0f, dvv * acc[j] + b1[choff + j]);

    float p0 = 0.f, p1 = 0.f, p2 = 0.f;
    for (int j = 0; j < 8; j++) {
        const float* wr = w2 + (choff + j) * 3;
        p0 += hr[j] * wr[0];
        p1 += hr[j] * wr[1];
        p2 += hr[j] * wr[2];
    }
    for (int off = 16; off > 0; off >>= 1) {
        p0 += __shfl_down(p0, off, 32);
        p1 += __shfl_down(p1, off, 32);
        p2 += __shfl_down(p2, off, 32);
    }
    if (l32 == 0) {
        p0 += b2[0]; p1 += b2[1]; p2 += b2[2];
        float m = fmaxf(p0, fmaxf(p1, p2));
        float l = logf(expf(p0 - m) + expf(p1 - m) + expf(p2 - m));
        out[(size_t)v * 3 + 0] = p0 - m - l;
        out[(size_t)v * 3 + 1] = p1 - m - l;
        out[(size_t)v * 3 + 2] = p2 - m - l;
    }
}

extern "C" void kernel_launch(void* const* d_in, const int* in_sizes, int n_in,
                              void* d_out, int out_size, void* d_ws, size_t ws_size,
                              hipStream_t stream) {
    const float* x    = (const float*)d_in[0];
    const int*   ei   = (const int*)d_in[1];      // [2][N_EDGES]
    const float* W1   = (const float*)d_in[2];
    const float* b1   = (const float*)d_in[3];
    const float* W2   = (const float*)d_in[4];
    const float* b2   = (const float*)d_in[5];
    float* out = (float*)d_out;

    const int* src = ei;
    const int* dst = ei + N_EDGES;

    char* ws = (char*)d_ws;
    unsigned short* h_ws = (unsigned short*)(ws + H_OFF);
    int*   adj       = (int*)(ws + ADJ_OFF);
    int*   row_start = (int*)(ws + RS_OFF);
    int*   cursor    = (int*)(ws + CUR_OFF);
    int*   deg       = (int*)(ws + DEG_OFF);
    float* dinv      = (float*)(ws + DINV_OFF);
    short* w1t       = (short*)(ws + W1T_OFF);
    int*   bsum      = (int*)(ws + BSUM_OFF);

    init_kernel<<<(N_NODES + 255) / 256, 256, 0, stream>>>(deg, cursor);
    w1t_kernel<<<(HIDDEN * IN_DIM + 255) / 256, 256, 0, stream>>>(W1, w1t);
    count_kernel<<<(N_EDGES + 255) / 256, 256, 0, stream>>>(dst, deg);
    scan1_kernel<<<N_SBLK, SCAN_B, 0, stream>>>(deg, bsum);
    scan2_kernel<<<1, 512, 0, stream>>>(bsum);
    scan3_kernel<<<N_SBLK, SCAN_B, 0, stream>>>(deg, bsum, row_start, dinv);
    fill_kernel<<<(N_EDGES + 255) / 256, 256, 0, stream>>>(src, dst, row_start, cursor, adj);
    gemm1_kernel<<<dim3((N_NODES + 127) / 128, HIDDEN / 128), 256, 0, stream>>>(x, w1t, dinv, h_ws);
    aggregate_kernel<<<N_NODES / 8, 256, 0, stream>>>(h_ws, adj, row_start, dinv, b1, W2, b2, out);
}